// Round 23
// baseline (32.346 us; speedup 1.0000x reference)
//
#include <hip/hip_runtime.h>
#include <hip/hip_bf16.h>
#include <hip/hip_fp16.h>
#include <math.h>

#define NGENES 512
#define NB2 128                       // fine binset (128 bins)
#define HIST_ELEMS (NGENES * NB2)     // 65536 cells
#define NBLK 256                      // K1 blocks (1 per CU) == #chunk images
#define IMG_WORDS (HIST_ELEMS / 8)    // u4-packed image: 8192 u32 = 32 KB
#define NRED 32                       // reduced images (4 per XCD)
#define RED_WORDS (HIST_ELEMS / 4)    // u8-packed reduced image: 16384 u32 = 64 KB
#define UNROLL 4                      // unguarded load-batch depth
#define T_BYTES (HIST_ELEMS * 2)      // fp16 table: 128 KB

typedef int   v4i __attribute__((ext_vector_type(4)));
typedef unsigned int v4u __attribute__((ext_vector_type(4)));
typedef float v4f __attribute__((ext_vector_type(4)));

// searchsorted(side='left') index into the fine 128-bin grid, bw2 = 156.25.
__device__ __forceinline__ int fine_idx(int v) {
    int i = (4 * v - 1) / 625;      // v==0 -> -1/625 == 0 (trunc toward zero)
    i = i < 0 ? 0 : i;
    return i > 127 ? 127 : i;
}

// ---------------- K1: LDS-privatized histogram (u4), plain flush (8.2 us) ------
__global__ __launch_bounds__(1024) void hist_u4_kernel(const int* __restrict__ pos,
                                                       const int* __restrict__ gene,
                                                       unsigned int* __restrict__ partial,
                                                       int nm, int chunk) {
    __shared__ unsigned int lds[IMG_WORDS];
    const int p = blockIdx.x;

    v4u* lds4 = (v4u*)lds;
    for (int i = threadIdx.x; i < IMG_WORDS / 4; i += 1024) {
        v4u z = {0u, 0u, 0u, 0u};
        lds4[i] = z;
    }
    __syncthreads();

    const int start = p * chunk;            // chunk is a multiple of 4
    const int end   = min(start + chunk, nm);
    const int i4s = start >> 2;
    const int i4e = end >> 2;
    const v4i* p4 = (const v4i*)pos;
    const v4i* g4 = (const v4i*)gene;

    int base = i4s;
    for (; base + UNROLL * 1024 <= i4e; base += UNROLL * 1024) {
        v4i P[UNROLL], G[UNROLL];
#pragma unroll
        for (int k = 0; k < UNROLL; ++k) {
            const int i = base + k * 1024 + (int)threadIdx.x;
            P[k] = p4[i];
            G[k] = g4[i];
        }
#pragma unroll
        for (int k = 0; k < UNROLL; ++k) {
            int c0 = (G[k].x << 7) + fine_idx(P[k].x);
            int c1 = (G[k].y << 7) + fine_idx(P[k].y);
            int c2 = (G[k].z << 7) + fine_idx(P[k].z);
            int c3 = (G[k].w << 7) + fine_idx(P[k].w);
            atomicAdd(&lds[c0 >> 3], 1u << ((c0 & 7) << 2));
            atomicAdd(&lds[c1 >> 3], 1u << ((c1 & 7) << 2));
            atomicAdd(&lds[c2 >> 3], 1u << ((c2 & 7) << 2));
            atomicAdd(&lds[c3 >> 3], 1u << ((c3 & 7) << 2));
        }
    }
    for (int i = base + (int)threadIdx.x; i < i4e; i += 1024) {
        v4i pp = p4[i];
        v4i gg = g4[i];
        int c0 = (gg.x << 7) + fine_idx(pp.x);
        int c1 = (gg.y << 7) + fine_idx(pp.y);
        int c2 = (gg.z << 7) + fine_idx(pp.z);
        int c3 = (gg.w << 7) + fine_idx(pp.w);
        atomicAdd(&lds[c0 >> 3], 1u << ((c0 & 7) << 2));
        atomicAdd(&lds[c1 >> 3], 1u << ((c1 & 7) << 2));
        atomicAdd(&lds[c2 >> 3], 1u << ((c2 & 7) << 2));
        atomicAdd(&lds[c3 >> 3], 1u << ((c3 & 7) << 2));
    }
    for (int i = i4e * 4 + (int)threadIdx.x; i < end; i += 1024) {
        int c = (gene[i] << 7) + fine_idx(pos[i]);
        atomicAdd(&lds[c >> 3], 1u << ((c & 7) << 2));
    }
    __syncthreads();

    v4u* dst = (v4u*)(partial + (size_t)p * IMG_WORDS);
    for (int i = threadIdx.x; i < IMG_WORDS / 4; i += 1024) dst[i] = lds4[i];
}

// ---------------- K1.5: XCD-LOCAL 8:1 image reduction --------------------------
// Blocks dispatch round-robin over XCDs (blockIdx%8 = XCD -- perf heuristic
// only; correctness holds regardless). Block j (XCD j&7) sums the 8 u4 images
// written by K1 blocks b = (j&7) + 64*(j>>3) + 8i -- ALL resident-dirty in its
// OWN L2 (each XCD's 32 images = 1 MB < 4 MB L2) -> L2-hit reads instead of
// the ~0.9 TB/s cross-XCD dirty-line forwarding that cost K2 ~9 us (R21).
// Output: u8-expanded reduced images (nibble sums <= 8*15=120 < 255).
// Layout: red word 2w = even-nibble cells of orig word w (cells 8w+{0,2,4,6}
// as u8 lanes), word 2w+1 = odd cells.
__global__ __launch_bounds__(1024) void reduce_xcd_kernel(const unsigned int* __restrict__ partial,
                                                          unsigned int* __restrict__ red) {
    const int j = blockIdx.x;          // 0..31
    const int x = j & 7;               // XCD
    const int k = j >> 3;              // group within XCD
    unsigned int* dst = red + (size_t)j * RED_WORDS;
#pragma unroll
    for (int s = 0; s < 8; ++s) {
        const int w = s * 1024 + (int)threadIdx.x;
        unsigned int ae = 0u, ao = 0u;
#pragma unroll
        for (int i = 0; i < 8; ++i) {
            const int b = x + 64 * k + 8 * i;
            unsigned int v = partial[(size_t)b * IMG_WORDS + w];
            ae += v & 0x0F0F0F0Fu;
            ao += (v >> 4) & 0x0F0F0F0Fu;
        }
        dst[2 * w]     = ae;
        dst[2 * w + 1] = ao;
    }
}

// ---------------- fallback path: direct global atomics ----------------
__global__ void hist_kernel(const int* __restrict__ pos, const int* __restrict__ gene,
                            unsigned int* __restrict__ hist, int n) {
    const int tid = blockIdx.x * blockDim.x + threadIdx.x;
    const int stride = gridDim.x * blockDim.x;
    const int n4 = n >> 2;
    const v4i* p4 = (const v4i*)pos;
    const v4i* g4 = (const v4i*)gene;
    for (int i = tid; i < n4; i += stride) {
        v4i p = p4[i];
        v4i g = g4[i];
        atomicAdd(&hist[(g.x << 7) + fine_idx(p.x)], 1u);
        atomicAdd(&hist[(g.y << 7) + fine_idx(p.y)], 1u);
        atomicAdd(&hist[(g.z << 7) + fine_idx(p.z)], 1u);
        atomicAdd(&hist[(g.w << 7) + fine_idx(p.w)], 1u);
    }
    int t = n4 * 4 + tid;
    if (t < n) atomicAdd(&hist[(gene[t] << 7) + fine_idx(pos[t])], 1u);
}

// ---------------- table math ----------------
__device__ __forceinline__ float mlp32(float c, const float* __restrict__ W1k,
                                       const float* __restrict__ B1k,
                                       const float* __restrict__ W2k, float b2) {
    float s = b2;
#pragma unroll
    for (int h = 0; h < 32; ++h) {
        float v = fmaf(c, W1k[h], B1k[h]);
        v = v > 0.f ? v : 0.f;
        s = fmaf(v, W2k[h], s);
    }
    return s;
}

__device__ __forceinline__ float wave_max(float v) {
#pragma unroll
    for (int off = 32; off >= 1; off >>= 1) v = fmaxf(v, __shfl_xor(v, off));
    return v;
}
__device__ __forceinline__ float wave_sum(float v) {
#pragma unroll
    for (int off = 32; off >= 1; off >>= 1) v += __shfl_xor(v, off);
    return v;
}

__device__ __forceinline__ void table_math(int g, int t, float n2a, float n2b,
                                           const float* __restrict__ W1,
                                           const float* __restrict__ B1,
                                           const float* __restrict__ W2,
                                           const float* __restrict__ B2,
                                           __half* __restrict__ T) {
    float n1 = n2a + n2b;
    float n0 = __shfl(n1, 2 * t) + __shfl(n1, 2 * t + 1);

    float h2a = mlp32(n2a / 156.25f, W1 + 64, B1 + 64, W2 + 64, B2[2]);
    float h2b = mlp32(n2b / 156.25f, W1 + 64, B1 + 64, W2 + 64, B2[2]);
    float h1  = mlp32(n1  / 312.5f,  W1 + 32, B1 + 32, W2 + 32, B2[1]);
    float h0  = mlp32(n0  / 625.0f,  W1,      B1,      W2,      B2[0]);

    float m2 = wave_max(fmaxf(h2a, h2b));
    float s2 = wave_sum(expf(h2a - m2) + expf(h2b - m2));
    float l2 = m2 + logf(s2);

    float m1 = wave_max(h1);
    float s1 = wave_sum(expf(h1 - m1));
    float l1 = m1 + logf(s1);

    float h0m = (t < 32) ? h0 : -INFINITY;
    float m0 = wave_max(h0m);
    float s0 = wave_sum((t < 32) ? expf(h0 - m0) : 0.f);
    float l0 = m0 + logf(s0);

    const float CONST = logf(32.f) + logf(64.f) + logf(128.f) - logf(20000.f);

    float ls1 = h1 - l1;
    float ls0_own = h0 - l0;
    float ls0 = __shfl(ls0_own, t >> 1);

    float base = ls1 + ls0 + CONST;
    T[(g << 7) + 2 * t]     = __float2half((h2a - l2) + base);
    T[(g << 7) + 2 * t + 1] = __float2half((h2b - l2) + base);
}

// K2: block = gene-pair, reads its 2 lines from the 32 REDUCED images (2 MB
// total, exactly-once, coalesced). Thread t: image i=t>>5, orig-word q=t&31
// (orig word w=32b+q covers gene 2b+(q>>4), bins 8(q&15)..8(q&15)+7).
// LDS-atomic u16-pair merge, then waves 0/1 run table_math.
__global__ __launch_bounds__(1024) void table_from_red(const unsigned int* __restrict__ red,
                                                       const float* __restrict__ W1,
                                                       const float* __restrict__ B1,
                                                       const float* __restrict__ W2,
                                                       const float* __restrict__ B2,
                                                       __half* __restrict__ T) {
    const int b = blockIdx.x;              // gene pair (2b, 2b+1)
    const int t = threadIdx.x;
    __shared__ unsigned int binpair[128];  // [gl*64 + j]: cnt(2j) | cnt(2j+1)<<16
    if (t < 128) binpair[t] = 0u;
    __syncthreads();

    const int i = t >> 5;                  // reduced image 0..31
    const int q = t & 31;                  // orig u4-word within gene pair
    const unsigned int* src = red + (size_t)i * RED_WORDS + (b << 6) + 2 * q;
    const unsigned int ae = src[0];        // even cells (bins 8q'+{0,2,4,6})
    const unsigned int ao = src[1];        // odd  cells

    const int gl = q >> 4;
    const int jbase = gl * 64 + (q & 15) * 4;
#pragma unroll
    for (int jj = 0; jj < 4; ++jj) {
        unsigned int val = ((ae >> (8 * jj)) & 0xFFu) | (((ao >> (8 * jj)) & 0xFFu) << 16);
        atomicAdd(&binpair[jbase + jj], val);
    }
    __syncthreads();

    if (t < 128) {
        const int j  = t >> 6;             // 0/1 -> gene 2b+j
        const int ln = t & 63;
        unsigned int v = binpair[j * 64 + ln];
        table_math(2 * b + j, ln, (float)(v & 0xFFFFu), (float)(v >> 16),
                   W1, B1, W2, B2, T);
    }
}

__global__ __launch_bounds__(64) void table_from_hist(const unsigned int* __restrict__ hist,
                                                      const float* __restrict__ W1,
                                                      const float* __restrict__ B1,
                                                      const float* __restrict__ W2,
                                                      const float* __restrict__ B2,
                                                      __half* __restrict__ T) {
    const int g = blockIdx.x;
    const int t = threadIdx.x;
    const unsigned int* hg = hist + (g << 7);
    table_math(g, t, (float)hg[2 * t], (float)hg[2 * t + 1], W1, B1, W2, B2, T);
}

// K3: LDS-staged fp16 table gather -- measured 4.9 us slot (R18).
__global__ __launch_bounds__(1024) void gather_lds_kernel(const int* __restrict__ coord,
                                                          const int* __restrict__ gene,
                                                          const __half* __restrict__ Th,
                                                          float* __restrict__ out, int n) {
    extern __shared__ __half Tl[];
    {
        const v4u* src = (const v4u*)Th;
        v4u* dst = (v4u*)Tl;
#pragma unroll
        for (int k = 0; k < T_BYTES / 16 / 1024; ++k)
            dst[k * 1024 + threadIdx.x] = src[k * 1024 + threadIdx.x];
    }
    __syncthreads();

    const int tid = blockIdx.x * 1024 + (int)threadIdx.x;
    const int stride = NBLK * 1024;
    const int n8 = n >> 3;
    const v4i* c4 = (const v4i*)coord;
    const v4i* g4 = (const v4i*)gene;
    v4f* o4 = (v4f*)out;
    for (int i = tid; i < n8; i += stride) {
        v4i c0 = c4[2 * i];
        v4i c1 = c4[2 * i + 1];
        v4i g0 = g4[2 * i];
        v4i g1 = g4[2 * i + 1];
        v4f oa, ob;
        oa.x = __half2float(Tl[(g0.x << 7) + fine_idx(c0.x)]);
        oa.y = __half2float(Tl[(g0.y << 7) + fine_idx(c0.y)]);
        oa.z = __half2float(Tl[(g0.z << 7) + fine_idx(c0.z)]);
        oa.w = __half2float(Tl[(g0.w << 7) + fine_idx(c0.w)]);
        ob.x = __half2float(Tl[(g1.x << 7) + fine_idx(c1.x)]);
        ob.y = __half2float(Tl[(g1.y << 7) + fine_idx(c1.y)]);
        ob.z = __half2float(Tl[(g1.z << 7) + fine_idx(c1.z)]);
        ob.w = __half2float(Tl[(g1.w << 7) + fine_idx(c1.w)]);
        o4[2 * i]     = oa;
        o4[2 * i + 1] = ob;
    }
    for (int t = n8 * 8 + tid; t < n; t += stride)
        out[t] = __half2float(Tl[(gene[t] << 7) + fine_idx(coord[t])]);
}

// Fallback gather (global fp16 T).
__global__ __launch_bounds__(256) void frag_kernel(const int* __restrict__ coord,
                                                   const int* __restrict__ gene,
                                                   const __half* __restrict__ T,
                                                   float* __restrict__ out, int n) {
    const int tid = blockIdx.x * blockDim.x + threadIdx.x;
    const int stride = gridDim.x * blockDim.x;
    const int n4 = n >> 2;
    const v4i* c4 = (const v4i*)coord;
    const v4i* g4 = (const v4i*)gene;
    v4f* o4 = (v4f*)out;
    for (int i = tid; i < n4; i += stride) {
        v4i c = c4[i];
        v4i g = g4[i];
        v4f o;
        o.x = __half2float(T[(g.x << 7) + fine_idx(c.x)]);
        o.y = __half2float(T[(g.y << 7) + fine_idx(c.y)]);
        o.z = __half2float(T[(g.z << 7) + fine_idx(c.z)]);
        o.w = __half2float(T[(g.w << 7) + fine_idx(c.w)]);
        o4[i] = o;
    }
    for (int t = n4 * 4 + tid; t < n; t += stride)
        out[t] = __half2float(T[(gene[t] << 7) + fine_idx(coord[t])]);
}

extern "C" void kernel_launch(void* const* d_in, const int* in_sizes, int n_in,
                              void* d_out, int out_size, void* d_ws, size_t ws_size,
                              hipStream_t stream) {
    const int* coords = (const int*)d_in[0];
    const int* fgene  = (const int*)d_in[1];
    const int* mpos   = (const int*)d_in[2];
    const int* mgene  = (const int*)d_in[3];
    const float* W1 = (const float*)d_in[7];   // (3,1,32)
    const float* B1 = (const float*)d_in[8];   // (3,32)
    const float* W2 = (const float*)d_in[9];   // (3,32,1)
    const float* B2 = (const float*)d_in[10];  // (3,1)

    __half* Th = (__half*)d_ws;                                           // 128 KB
    unsigned int* hist = (unsigned int*)((char*)d_ws + T_BYTES);          // 256 KB (fallback)
    unsigned int* partial = (unsigned int*)((char*)d_ws + T_BYTES
                                            + HIST_ELEMS * sizeof(unsigned int));
    unsigned int* red = (unsigned int*)((char*)d_ws + T_BYTES
                                        + HIST_ELEMS * sizeof(unsigned int)
                                        + (size_t)NBLK * IMG_WORDS * sizeof(unsigned int));

    const int nf = in_sizes[0];
    const int nm = in_sizes[2];

    const size_t need = T_BYTES + HIST_ELEMS * sizeof(unsigned int)
                      + (size_t)NBLK * IMG_WORDS * sizeof(unsigned int)   // 8 MB partials
                      + (size_t)NRED * RED_WORDS * sizeof(unsigned int);  // 2 MB reduced

    if (ws_size >= need) {
        int chunk = ((nm + NBLK - 1) / NBLK + 3) & ~3;   // multiple of 4
        hist_u4_kernel<<<NBLK, 1024, 0, stream>>>(mpos, mgene, partial, nm, chunk);
        reduce_xcd_kernel<<<NRED, 1024, 0, stream>>>(partial, red);
        table_from_red<<<NGENES / 2, 1024, 0, stream>>>(red, W1, B1, W2, B2, Th);
        gather_lds_kernel<<<NBLK, 1024, T_BYTES, stream>>>(coords, fgene, Th, (float*)d_out, nf);
    } else {
        (void)hipMemsetAsync(hist, 0, HIST_ELEMS * sizeof(unsigned int), stream);
        hist_kernel<<<2048, 256, 0, stream>>>(mpos, mgene, hist, nm);
        table_from_hist<<<NGENES, 64, 0, stream>>>(hist, W1, B1, W2, B2, Th);
        frag_kernel<<<1024, 256, 0, stream>>>(coords, fgene, Th, (float*)d_out, nf);
    }
}

// Round 24
// 27.234 us; speedup vs baseline: 1.1877x; 1.1877x over previous
//
#include <hip/hip_runtime.h>
#include <hip/hip_bf16.h>
#include <hip/hip_fp16.h>
#include <math.h>

#define NGENES 512
#define NB2 128                       // fine binset (128 bins)
#define HIST_ELEMS (NGENES * NB2)     // 65536 cells
#define NBLK 256                      // blocks (1 per CU); also = #chunk images
#define IMG_WORDS (HIST_ELEMS / 8)    // u4-packed image: 8192 u32 = 32 KB
#define UNROLL 4                      // unguarded load-batch depth
#define T_BYTES (HIST_ELEMS * 2)      // fp16 table: 128 KB

typedef int   v4i __attribute__((ext_vector_type(4)));
typedef unsigned int v4u __attribute__((ext_vector_type(4)));
typedef float v4f __attribute__((ext_vector_type(4)));

// searchsorted(side='left') index into the fine 128-bin grid, bw2 = 156.25.
__device__ __forceinline__ int fine_idx(int v) {
    int i = (4 * v - 1) / 625;      // v==0 -> -1/625 == 0 (trunc toward zero)
    i = i < 0 ? 0 : i;
    return i > 127 ? 127 : i;
}

// ---------------- K1: LDS-privatized histogram (u4), write-through flush -------
// Best-measured config (R22, 27.25 us total). Main loop 8.2 us (measured R15).
__global__ __launch_bounds__(1024) void hist_u4_kernel(const int* __restrict__ pos,
                                                       const int* __restrict__ gene,
                                                       unsigned int* __restrict__ partial,
                                                       int nm, int chunk) {
    __shared__ unsigned int lds[IMG_WORDS];
    const int p = blockIdx.x;

    v4u* lds4 = (v4u*)lds;
    for (int i = threadIdx.x; i < IMG_WORDS / 4; i += 1024) {
        v4u z = {0u, 0u, 0u, 0u};
        lds4[i] = z;
    }
    __syncthreads();

    const int start = p * chunk;            // chunk is a multiple of 4
    const int end   = min(start + chunk, nm);
    const int i4s = start >> 2;
    const int i4e = end >> 2;
    const v4i* p4 = (const v4i*)pos;
    const v4i* g4 = (const v4i*)gene;

    int base = i4s;
    for (; base + UNROLL * 1024 <= i4e; base += UNROLL * 1024) {
        v4i P[UNROLL], G[UNROLL];
#pragma unroll
        for (int k = 0; k < UNROLL; ++k) {
            const int i = base + k * 1024 + (int)threadIdx.x;
            P[k] = p4[i];
            G[k] = g4[i];
        }
#pragma unroll
        for (int k = 0; k < UNROLL; ++k) {
            int c0 = (G[k].x << 7) + fine_idx(P[k].x);
            int c1 = (G[k].y << 7) + fine_idx(P[k].y);
            int c2 = (G[k].z << 7) + fine_idx(P[k].z);
            int c3 = (G[k].w << 7) + fine_idx(P[k].w);
            atomicAdd(&lds[c0 >> 3], 1u << ((c0 & 7) << 2));
            atomicAdd(&lds[c1 >> 3], 1u << ((c1 & 7) << 2));
            atomicAdd(&lds[c2 >> 3], 1u << ((c2 & 7) << 2));
            atomicAdd(&lds[c3 >> 3], 1u << ((c3 & 7) << 2));
        }
    }
    for (int i = base + (int)threadIdx.x; i < i4e; i += 1024) {
        v4i pp = p4[i];
        v4i gg = g4[i];
        int c0 = (gg.x << 7) + fine_idx(pp.x);
        int c1 = (gg.y << 7) + fine_idx(pp.y);
        int c2 = (gg.z << 7) + fine_idx(pp.z);
        int c3 = (gg.w << 7) + fine_idx(pp.w);
        atomicAdd(&lds[c0 >> 3], 1u << ((c0 & 7) << 2));
        atomicAdd(&lds[c1 >> 3], 1u << ((c1 & 7) << 2));
        atomicAdd(&lds[c2 >> 3], 1u << ((c2 & 7) << 2));
        atomicAdd(&lds[c3 >> 3], 1u << ((c3 & 7) << 2));
    }
    for (int i = i4e * 4 + (int)threadIdx.x; i < end; i += 1024) {
        int c = (gene[i] << 7) + fine_idx(pos[i]);
        atomicAdd(&lds[c >> 3], 1u << ((c & 7) << 2));
    }
    __syncthreads();

    // write-through flush: agent-scope atomic u64 stores (4 per thread)
    unsigned long long* dst = (unsigned long long*)(partial + (size_t)p * IMG_WORDS);
    const unsigned long long* src = (const unsigned long long*)lds;
    for (int i = threadIdx.x; i < IMG_WORDS / 2; i += 1024)
        __hip_atomic_store(&dst[i], src[i], __ATOMIC_RELAXED, __HIP_MEMORY_SCOPE_AGENT);
}

// ---------------- fallback path: direct global atomics ----------------
__global__ void hist_kernel(const int* __restrict__ pos, const int* __restrict__ gene,
                            unsigned int* __restrict__ hist, int n) {
    const int tid = blockIdx.x * blockDim.x + threadIdx.x;
    const int stride = gridDim.x * blockDim.x;
    const int n4 = n >> 2;
    const v4i* p4 = (const v4i*)pos;
    const v4i* g4 = (const v4i*)gene;
    for (int i = tid; i < n4; i += stride) {
        v4i p = p4[i];
        v4i g = g4[i];
        atomicAdd(&hist[(g.x << 7) + fine_idx(p.x)], 1u);
        atomicAdd(&hist[(g.y << 7) + fine_idx(p.y)], 1u);
        atomicAdd(&hist[(g.z << 7) + fine_idx(p.z)], 1u);
        atomicAdd(&hist[(g.w << 7) + fine_idx(p.w)], 1u);
    }
    int t = n4 * 4 + tid;
    if (t < n) atomicAdd(&hist[(gene[t] << 7) + fine_idx(pos[t])], 1u);
}

// ---------------- table math ----------------
__device__ __forceinline__ float mlp32(float c, const float* __restrict__ W1k,
                                       const float* __restrict__ B1k,
                                       const float* __restrict__ W2k, float b2) {
    float s = b2;
#pragma unroll
    for (int h = 0; h < 32; ++h) {
        float v = fmaf(c, W1k[h], B1k[h]);
        v = v > 0.f ? v : 0.f;
        s = fmaf(v, W2k[h], s);
    }
    return s;
}

__device__ __forceinline__ float wave_max(float v) {
#pragma unroll
    for (int off = 32; off >= 1; off >>= 1) v = fmaxf(v, __shfl_xor(v, off));
    return v;
}
__device__ __forceinline__ float wave_sum(float v) {
#pragma unroll
    for (int off = 32; off >= 1; off >>= 1) v += __shfl_xor(v, off);
    return v;
}

__device__ __forceinline__ void table_math(int g, int t, float n2a, float n2b,
                                           const float* __restrict__ W1,
                                           const float* __restrict__ B1,
                                           const float* __restrict__ W2,
                                           const float* __restrict__ B2,
                                           __half* __restrict__ T) {
    float n1 = n2a + n2b;
    float n0 = __shfl(n1, 2 * t) + __shfl(n1, 2 * t + 1);

    float h2a = mlp32(n2a / 156.25f, W1 + 64, B1 + 64, W2 + 64, B2[2]);
    float h2b = mlp32(n2b / 156.25f, W1 + 64, B1 + 64, W2 + 64, B2[2]);
    float h1  = mlp32(n1  / 312.5f,  W1 + 32, B1 + 32, W2 + 32, B2[1]);
    float h0  = mlp32(n0  / 625.0f,  W1,      B1,      W2,      B2[0]);

    float m2 = wave_max(fmaxf(h2a, h2b));
    float s2 = wave_sum(expf(h2a - m2) + expf(h2b - m2));
    float l2 = m2 + logf(s2);

    float m1 = wave_max(h1);
    float s1 = wave_sum(expf(h1 - m1));
    float l1 = m1 + logf(s1);

    float h0m = (t < 32) ? h0 : -INFINITY;
    float m0 = wave_max(h0m);
    float s0 = wave_sum((t < 32) ? expf(h0 - m0) : 0.f);
    float l0 = m0 + logf(s0);

    const float CONST = logf(32.f) + logf(64.f) + logf(128.f) - logf(20000.f);

    float ls1 = h1 - l1;
    float ls0_own = h0 - l0;
    float ls0 = __shfl(ls0_own, t >> 1);

    float base = ls1 + ls0 + CONST;
    T[(g << 7) + 2 * t]     = __float2half((h2a - l2) + base);
    T[(g << 7) + 2 * t + 1] = __float2half((h2b - l2) + base);
}

// K2: gene-pair blocks, exactly-once full-line reads.
__global__ __launch_bounds__(1024) void table_from_partial(const unsigned int* __restrict__ partial,
                                                           const float* __restrict__ W1,
                                                           const float* __restrict__ B1,
                                                           const float* __restrict__ W2,
                                                           const float* __restrict__ B2,
                                                           __half* __restrict__ T) {
    const int b = blockIdx.x;              // gene pair (2b, 2b+1)
    const int t = threadIdx.x;
    __shared__ unsigned int binpair[128];  // [gl*64 + j]: cnt(2j) | cnt(2j+1)<<16
    if (t < 128) binpair[t] = 0u;
    __syncthreads();

    const int pos = t & 31;                // u32 within the 128B line
    const int img0 = t >> 5;               // 0..31
    const unsigned int* src = partial + (size_t)img0 * IMG_WORDS + (b << 5) + pos;

    unsigned int ae = 0u, ao = 0u;
#pragma unroll
    for (int r = 0; r < 8; ++r) {
        unsigned int w = src[(size_t)r * 32 * IMG_WORDS];
        ae += w & 0x0F0F0F0Fu;
        ao += (w >> 4) & 0x0F0F0F0Fu;
    }
    const int gl = pos >> 4;
    const int jbase = gl * 64 + (pos & 15) * 4;
#pragma unroll
    for (int k = 0; k < 4; ++k) {
        unsigned int val = ((ae >> (8 * k)) & 0xFFu) | (((ao >> (8 * k)) & 0xFFu) << 16);
        atomicAdd(&binpair[jbase + k], val);
    }
    __syncthreads();

    if (t < 128) {
        const int j  = t >> 6;             // 0/1 -> gene 2b+j
        const int ln = t & 63;
        unsigned int v = binpair[j * 64 + ln];
        table_math(2 * b + j, ln, (float)(v & 0xFFFFu), (float)(v >> 16),
                   W1, B1, W2, B2, T);
    }
}

__global__ __launch_bounds__(64) void table_from_hist(const unsigned int* __restrict__ hist,
                                                      const float* __restrict__ W1,
                                                      const float* __restrict__ B1,
                                                      const float* __restrict__ W2,
                                                      const float* __restrict__ B2,
                                                      __half* __restrict__ T) {
    const int g = blockIdx.x;
    const int t = threadIdx.x;
    const unsigned int* hg = hist + (g << 7);
    table_math(g, t, (float)hg[2 * t], (float)hg[2 * t + 1], W1, B1, W2, B2, T);
}

// K3: LDS-staged fp16 table gather -- measured 4.9 us slot (R18).
__global__ __launch_bounds__(1024) void gather_lds_kernel(const int* __restrict__ coord,
                                                          const int* __restrict__ gene,
                                                          const __half* __restrict__ Th,
                                                          float* __restrict__ out, int n) {
    extern __shared__ __half Tl[];
    {
        const v4u* src = (const v4u*)Th;
        v4u* dst = (v4u*)Tl;
#pragma unroll
        for (int k = 0; k < T_BYTES / 16 / 1024; ++k)
            dst[k * 1024 + threadIdx.x] = src[k * 1024 + threadIdx.x];
    }
    __syncthreads();

    const int tid = blockIdx.x * 1024 + (int)threadIdx.x;
    const int stride = NBLK * 1024;
    const int n8 = n >> 3;
    const v4i* c4 = (const v4i*)coord;
    const v4i* g4 = (const v4i*)gene;
    v4f* o4 = (v4f*)out;
    for (int i = tid; i < n8; i += stride) {
        v4i c0 = c4[2 * i];
        v4i c1 = c4[2 * i + 1];
        v4i g0 = g4[2 * i];
        v4i g1 = g4[2 * i + 1];
        v4f oa, ob;
        oa.x = __half2float(Tl[(g0.x << 7) + fine_idx(c0.x)]);
        oa.y = __half2float(Tl[(g0.y << 7) + fine_idx(c0.y)]);
        oa.z = __half2float(Tl[(g0.z << 7) + fine_idx(c0.z)]);
        oa.w = __half2float(Tl[(g0.w << 7) + fine_idx(c0.w)]);
        ob.x = __half2float(Tl[(g1.x << 7) + fine_idx(c1.x)]);
        ob.y = __half2float(Tl[(g1.y << 7) + fine_idx(c1.y)]);
        ob.z = __half2float(Tl[(g1.z << 7) + fine_idx(c1.z)]);
        ob.w = __half2float(Tl[(g1.w << 7) + fine_idx(c1.w)]);
        o4[2 * i]     = oa;
        o4[2 * i + 1] = ob;
    }
    for (int t = n8 * 8 + tid; t < n; t += stride)
        out[t] = __half2float(Tl[(gene[t] << 7) + fine_idx(coord[t])]);
}

// Fallback gather (global fp16 T).
__global__ __launch_bounds__(256) void frag_kernel(const int* __restrict__ coord,
                                                   const int* __restrict__ gene,
                                                   const __half* __restrict__ T,
                                                   float* __restrict__ out, int n) {
    const int tid = blockIdx.x * blockDim.x + threadIdx.x;
    const int stride = gridDim.x * blockDim.x;
    const int n4 = n >> 2;
    const v4i* c4 = (const v4i*)coord;
    const v4i* g4 = (const v4i*)gene;
    v4f* o4 = (v4f*)out;
    for (int i = tid; i < n4; i += stride) {
        v4i c = c4[i];
        v4i g = g4[i];
        v4f o;
        o.x = __half2float(T[(g.x << 7) + fine_idx(c.x)]);
        o.y = __half2float(T[(g.y << 7) + fine_idx(c.y)]);
        o.z = __half2float(T[(g.z << 7) + fine_idx(c.z)]);
        o.w = __half2float(T[(g.w << 7) + fine_idx(c.w)]);
        o4[i] = o;
    }
    for (int t = n4 * 4 + tid; t < n; t += stride)
        out[t] = __half2float(T[(gene[t] << 7) + fine_idx(coord[t])]);
}

extern "C" void kernel_launch(void* const* d_in, const int* in_sizes, int n_in,
                              void* d_out, int out_size, void* d_ws, size_t ws_size,
                              hipStream_t stream) {
    const int* coords = (const int*)d_in[0];
    const int* fgene  = (const int*)d_in[1];
    const int* mpos   = (const int*)d_in[2];
    const int* mgene  = (const int*)d_in[3];
    const float* W1 = (const float*)d_in[7];   // (3,1,32)
    const float* B1 = (const float*)d_in[8];   // (3,32)
    const float* W2 = (const float*)d_in[9];   // (3,32,1)
    const float* B2 = (const float*)d_in[10];  // (3,1)

    __half* Th = (__half*)d_ws;                                           // 128 KB
    unsigned int* hist = (unsigned int*)((char*)d_ws + T_BYTES);          // 256 KB (fallback)
    unsigned int* partial = (unsigned int*)((char*)d_ws + T_BYTES
                                            + HIST_ELEMS * sizeof(unsigned int));

    const int nf = in_sizes[0];
    const int nm = in_sizes[2];

    const size_t need = T_BYTES + HIST_ELEMS * sizeof(unsigned int)
                      + (size_t)NBLK * IMG_WORDS * sizeof(unsigned int);  // ~8.4 MB

    if (ws_size >= need) {
        int chunk = ((nm + NBLK - 1) / NBLK + 3) & ~3;   // multiple of 4
        hist_u4_kernel<<<NBLK, 1024, 0, stream>>>(mpos, mgene, partial, nm, chunk);
        table_from_partial<<<NGENES / 2, 1024, 0, stream>>>(partial, W1, B1, W2, B2, Th);
        gather_lds_kernel<<<NBLK, 1024, T_BYTES, stream>>>(coords, fgene, Th, (float*)d_out, nf);
    } else {
        (void)hipMemsetAsync(hist, 0, HIST_ELEMS * sizeof(unsigned int), stream);
        hist_kernel<<<2048, 256, 0, stream>>>(mpos, mgene, hist, nm);
        table_from_hist<<<NGENES, 64, 0, stream>>>(hist, W1, B1, W2, B2, Th);
        frag_kernel<<<1024, 256, 0, stream>>>(coords, fgene, Th, (float*)d_out, nf);
    }
}